// Round 4
// baseline (452.831 us; speedup 1.0000x reference)
//
#include <hip/hip_runtime.h>
#include <math.h>

// Problem constants (fixed shapes from reference)
#define B_   64
#define T_   2048
#define ENC_ 512
#define U_   128
#define NC   16      // K chunks of 32
#define MBLK 32      // rows per block (full-K resident in LDS)

typedef __attribute__((ext_vector_type(8))) _Float16 half8;
typedef __attribute__((ext_vector_type(4))) _Float16 half4;
typedef __attribute__((ext_vector_type(4))) float float4v;

// split x into hi (RTN fp16) + lo (fp16 of remainder): combined err ~2^-22|x|
__device__ inline void cvt_split4(const float4 a, half4& h, half4& l) {
    const float xs[4] = {a.x, a.y, a.z, a.w};
#pragma unroll
    for (int j = 0; j < 4; ++j) {
        const _Float16 hi = (_Float16)xs[j];
        h[j] = hi;
        l[j] = (_Float16)(xs[j] - (float)hi);
    }
}

// tanh via single v_exp: 1 - 2/(e^{2x}+1); exact at ±inf, err ~1e-6
__device__ inline float fast_tanh(float x) {
    const float e = __expf(2.0f * x);
    return 1.0f - 2.0f / (e + 1.0f);
}

// ---------------------------------------------------------------------------
// Prep kernel (merged): blocks 0..63 qproj; 64..95 wprep; 96..224 zero.
//  qproj: q'[b][u] = dh[b,:]@Wa[:,u] + ba[u] + bb[u]  (bb folded; bv cancels)
//  wprep: Wb -> MFMA B-frag order, single fp16 (RTN).
//         B-frag (16x16x32): lane L holds B[k=(L>>4)*8+j][n=(L&15)].
//         frag f = c*8+gn; whf[(f*64+L)*8+j]; chunk c = contiguous 8 KB.
//  zero:  uctx (32768) + Zsum (64)
// ---------------------------------------------------------------------------
__global__ __launch_bounds__(256)
void prep_kernel(const float* __restrict__ dh,
                 const float* __restrict__ Wa,
                 const float* __restrict__ ba,
                 const float* __restrict__ bb,
                 const float* __restrict__ Wb,
                 float* __restrict__ q,
                 _Float16* __restrict__ whf,
                 float* __restrict__ uz) {
    const int blk = blockIdx.x;
    const int tid = threadIdx.x;
    if (blk < 64) {
        if (tid < U_) {
            const int b = blk, u = tid;
            const float* dhb = dh + b * ENC_;
            float a0 = 0.f, a1 = 0.f, a2 = 0.f, a3 = 0.f;
#pragma unroll 4
            for (int e = 0; e < ENC_; e += 4) {
                a0 += dhb[e + 0] * Wa[(e + 0) * U_ + u];
                a1 += dhb[e + 1] * Wa[(e + 1) * U_ + u];
                a2 += dhb[e + 2] * Wa[(e + 2) * U_ + u];
                a3 += dhb[e + 3] * Wa[(e + 3) * U_ + u];
            }
            q[b * U_ + u] = ((a0 + a1) + (a2 + a3)) + ba[u] + bb[u];
        }
    } else if (blk < 96) {
        const int fid = (blk - 64) * 4 + (tid >> 6);   // 0..127
        const int c   = fid >> 3;
        const int gn  = fid & 7;
        const int L   = tid & 63;
        const int n   = gn * 16 + (L & 15);
        const int k0  = c * 32 + (L >> 4) * 8;
        half8 hi;
#pragma unroll
        for (int j = 0; j < 8; ++j)
            hi[j] = (_Float16)Wb[(size_t)(k0 + j) * U_ + n];
        *(half8*)(whf + ((size_t)fid * 64 + L) * 8) = hi;
    } else {
        const int i = (blk - 96) * 256 + tid;
        if (i < B_ * ENC_ + B_) uz[i] = 0.f;
    }
}

// ---------------------------------------------------------------------------
// Kernel B v5: fused score GEMM + exp + context. ROW-BURST restructure.
// v4 post-mortem: K-chunked staging revisits each enc row 16x at 128 B per
// visit with ~5us gaps -> 65K sparse DRAM streams, every access a row-miss
// -> 1.67 TB/s effective (21%). Fix: read each row ONCE, contiguously.
//
// Block = 32 rows x 128 U, full K=512 resident in LDS as split-f16:
//  STAGE: each 64-lane group loads one full 2-KB row per round (dense 1-KB
//    coalesced float4 loads, 16 loads/thread issued back-to-back = 64 KB
//    in flight per block). cvt fp32->hi/lo f16 ONCE, ds_write into
//    octet-XOR-swizzled planes: element (r,k) -> plane[r*512 +
//    ((k>>3)^(r&7))*8 + (k&7)]. One __syncthreads.
//  K-LOOP (no barriers, no inline asm, fully unrolled): per chunk per wave:
//    2x ds_read_b128 (A hi/lo frags, conflict-free by swizzle) + 4x b128
//    B-loads (whf, L2-resident, register-prefetched 2 chunks ahead via
//    3-buffer static rotation) + 8 MFMA. Compiler schedules/hoists freely.
//  Wave tile 16 rows x 64 U: waves (wr,wc) in 2x2 grid; acc = 4x float4.
//  EPILOGUE: tanh*Wv partial per wave over its 64 u, cross-U-half LDS
//    reduce, e=exp(s) (no max-sub: |s| <= ||Wv||_1 ~ 11, fp32-safe).
//  PHASE 2: context from LDS (hi+lo reconstruct, bank-minimal) ->
//    atomicAdd unnorm context. No global enc re-read at all.
// LDS 64.4 KB -> 2 blocks/CU; ~100 VGPR. Grid 4096.
// ---------------------------------------------------------------------------
__global__ __launch_bounds__(256, 2)
void score_ctx_kernel(const float* __restrict__ enc,
                      const _Float16* __restrict__ whf,
                      const float* __restrict__ q,
                      const float* __restrict__ Wv,
                      float* __restrict__ expw,
                      float* __restrict__ uctx,
                      float* __restrict__ Zsum) {
    __shared__ __align__(16) _Float16 Ah[MBLK * ENC_];   // 32 KB hi plane
    __shared__ __align__(16) _Float16 Al[MBLK * ENC_];   // 32 KB lo plane
    __shared__ float sred[2 * MBLK];
    __shared__ float ew[MBLK];

    const int tid = threadIdx.x;
    const int w   = tid >> 6;       // wave 0..3
    const int L   = tid & 63;
    const int m0  = blockIdx.x * MBLK;
    const int b   = m0 >> 11;       // blocks never straddle a batch

    // ================= STAGE: 32 rows x 2 KB, row-contiguous ==============
    {
        const int l = L;            // lane in 64-group
        const int g = w;            // group = wave: rows g, g+4, ..., g+28
        float4 xa[8], xb[8];
#pragma unroll
        for (int j = 0; j < 8; ++j) {
            const float* rp = enc + (size_t)(m0 + j * 4 + g) * ENC_;
            xa[j] = *(const float4*)(rp + l * 4);          // floats l*4..+3
            xb[j] = *(const float4*)(rp + 256 + l * 4);    // second KB
        }
#pragma unroll
        for (int j = 0; j < 8; ++j) {
            const int row = j * 4 + g;
            const int rs  = row & 7;
            const int rb  = row * ENC_;
            {   // xa: f0 = l*4 -> octet l>>1, half (l&1)
                half4 h, lo; cvt_split4(xa[j], h, lo);
                const int off = rb + (((l >> 1) ^ rs) * 8) + (l & 1) * 4;
                *(half4*)(Ah + off) = h;  *(half4*)(Al + off) = lo;
            }
            {   // xb: f0 = 256 + l*4 -> octet 32+(l>>1)
                half4 h, lo; cvt_split4(xb[j], h, lo);
                const int off = rb + ((((l >> 1) + 32) ^ rs) * 8) + (l & 1) * 4;
                *(half4*)(Ah + off) = h;  *(half4*)(Al + off) = lo;
            }
        }
    }
    __syncthreads();

    // ================= K-LOOP: pure LDS + L2-B, no barriers ===============
    const int wr  = w >> 1;         // row half (16 rows)
    const int wc  = w & 1;          // U half (64 cols)
    const int n15 = L & 15;
    const int aq  = L >> 4;         // k-quarter 0..3
    const int arow  = wr * 16 + n15;
    const int abase = arow * ENC_;
    const int ars   = arow & 7;

    float4v acc[4];
#pragma unroll
    for (int gi = 0; gi < 4; ++gi) acc[gi] = (float4v)0.f;

    half8 pb[3][4];                 // 3-deep B rotation (static under unroll)
#pragma unroll
    for (int gi = 0; gi < 4; ++gi) {
        pb[0][gi] = *(const half8*)(whf + ((size_t)((0 * 8 + wc * 4 + gi) * 64 + L)) * 8);
        pb[1][gi] = *(const half8*)(whf + ((size_t)((1 * 8 + wc * 4 + gi) * 64 + L)) * 8);
    }

#pragma unroll
    for (int c = 0; c < NC; ++c) {
        if (c + 2 < NC) {
#pragma unroll
            for (int gi = 0; gi < 4; ++gi)
                pb[(c + 2) % 3][gi] = *(const half8*)(whf +
                    ((size_t)(((c + 2) * 8 + wc * 4 + gi) * 64 + L)) * 8);
        }
        const int slot = (c * 4 + aq) ^ ars;
        const half8 ah = *(const half8*)(Ah + abase + slot * 8);
        const half8 al = *(const half8*)(Al + abase + slot * 8);
#pragma unroll
        for (int gi = 0; gi < 4; ++gi) {
            acc[gi] = __builtin_amdgcn_mfma_f32_16x16x32_f16(ah, pb[c % 3][gi], acc[gi], 0, 0, 0);
            acc[gi] = __builtin_amdgcn_mfma_f32_16x16x32_f16(al, pb[c % 3][gi], acc[gi], 0, 0, 0);
        }
    }

    // ================= EPILOGUE: tanh + Wv partial dot ====================
    // C/D layout: col(u) = wc*64 + gi*16 + n15, row = wr*16 + (L>>4)*4 + r
    float qv[4], wvv[4];
#pragma unroll
    for (int gi = 0; gi < 4; ++gi) {
        const int u = wc * 64 + gi * 16 + n15;
        qv[gi]  = q[b * U_ + u];
        wvv[gi] = Wv[u];
    }
#pragma unroll
    for (int r = 0; r < 4; ++r) {
        float s = 0.f;
#pragma unroll
        for (int gi = 0; gi < 4; ++gi)
            s += fast_tanh(qv[gi] + acc[gi][r]) * wvv[gi];
        s += __shfl_xor(s, 1, 64);
        s += __shfl_xor(s, 2, 64);
        s += __shfl_xor(s, 4, 64);
        s += __shfl_xor(s, 8, 64);
        if (n15 == 0) {
            const int brow = wr * 16 + (L >> 4) * 4 + r;
            sred[wc * MBLK + brow] = s;
        }
    }
    __syncthreads();

    if (tid < MBLK) {
        const float s = sred[tid] + sred[MBLK + tid];
        const float e = __expf(s);
        ew[tid] = e;
        expw[m0 + tid] = e;
    }
    __syncthreads();

    // ================= PHASE 2: context from LDS ==========================
    // Thread t: cols (t*2, t*2+1); element (r,k): plane[r*512 +
    // ((k>>3)^(r&7))*8 + (k&7)], k=t*2 -> oct t>>2, in-oct (t&3)*2.
    typedef __attribute__((ext_vector_type(2))) _Float16 half2v;
    const int p2oct = tid >> 2;
    const int p2in  = (tid & 3) * 2;
    float sx = 0.f, sy = 0.f;
#pragma unroll 8
    for (int r = 0; r < MBLK; ++r) {
        const int off = r * ENC_ + ((p2oct ^ (r & 7)) * 8) + p2in;
        const half2v h = *(const half2v*)(Ah + off);
        const half2v lo = *(const half2v*)(Al + off);
        const float wgt = ew[r];
        sx += wgt * ((float)h[0] + (float)lo[0]);
        sy += wgt * ((float)h[1] + (float)lo[1]);
    }
    const int col = tid * 2;
    atomicAdd(&uctx[b * ENC_ + col], sx);
    atomicAdd(&uctx[b * ENC_ + col + 1], sy);

    if (tid < MBLK) {
        float z = ew[tid];
        z += __shfl_xor(z, 1, 64);
        z += __shfl_xor(z, 2, 64);
        z += __shfl_xor(z, 4, 64);
        z += __shfl_xor(z, 8, 64);
        z += __shfl_xor(z, 16, 64);
        if (tid == 0) atomicAdd(&Zsum[b], z);
    }
}

// ---------------------------------------------------------------------------
// Kernel N: normalize — ctx = uctx/Z, attn = expw/Z.
// ---------------------------------------------------------------------------
__global__ void normalize_kernel(const float* __restrict__ uctx,
                                 const float* __restrict__ Zsum,
                                 const float* __restrict__ expw,
                                 float* __restrict__ ctx,
                                 float* __restrict__ attn) {
    const int idx = blockIdx.x * 256 + threadIdx.x;
    if (idx < B_ * ENC_) {
        ctx[idx] = uctx[idx] / Zsum[idx >> 9];        // ENC_ = 512
    } else {
        const int i2 = idx - B_ * ENC_;
        attn[i2] = expw[i2] / Zsum[i2 >> 11];         // T_ = 2048
    }
}

// ---------------------------------------------------------------------------
extern "C" void kernel_launch(void* const* d_in, const int* in_sizes, int n_in,
                              void* d_out, int out_size, void* d_ws, size_t ws_size,
                              hipStream_t stream) {
    const float* dh  = (const float*)d_in[0];  // [64,512]
    const float* enc = (const float*)d_in[1];  // [64,2048,512]
    const float* Wa  = (const float*)d_in[2];  // [512,128]
    const float* ba  = (const float*)d_in[3];  // [128]
    const float* Wb  = (const float*)d_in[4];  // [512,128]
    const float* bb  = (const float*)d_in[5];  // [128]
    const float* Wv  = (const float*)d_in[6];  // [128,1]
    // d_in[7] = bv — cancels in softmax, unused.

    float* out      = (float*)d_out;
    float* ctx      = out;                 // [64,512]
    float* attn_out = out + (B_ * ENC_);   // [64,2048]

    float* ws   = (float*)d_ws;
    float* q    = ws;                              // 8192
    float* expw = ws + 8192;                       // 131072
    float* uctx = ws + 8192 + B_ * T_;             // 32768
    float* Zs   = uctx + B_ * ENC_;                // 64
    _Float16* whf = (_Float16*)(Zs + 64);          // 65536 halfs (128 KB)

    prep_kernel<<<225, 256, 0, stream>>>(dh, Wa, ba, bb, Wb, q, whf, uctx);
    score_ctx_kernel<<<(B_ * T_) / MBLK, 256, 0, stream>>>(enc, whf, q, Wv,
                                                           expw, uctx, Zs);
    normalize_kernel<<<(B_ * (ENC_ + T_)) / 256, 256, 0, stream>>>(uctx, Zs, expw,
                                                                   ctx, attn_out);
}